// Round 4
// baseline (501.269 us; speedup 1.0000x reference)
//
#include <hip/hip_runtime.h>

#define T_DIM 512
#define C_DIM 48
#define BPS   64          // bp row stride (padded to 64 so all lanes store)
#define CH    4           // chunk: prefetch distance, ring-sync granularity
#define RING  8           // score/max ring rows (power of 2)
#define RMASK (RING - 1)

typedef float f32x2 __attribute__((ext_vector_type(2)));
typedef float f32x4 __attribute__((ext_vector_type(4)));

#if __has_builtin(__builtin_amdgcn_readlane)
#define READLANE_I(v, l) __builtin_amdgcn_readlane((v), (l))
#else
#define READLANE_I(v, l) __shfl((v), (l), 64)
#endif

#if __has_builtin(__builtin_amdgcn_s_sleep)
#define SPIN_PAUSE() __builtin_amdgcn_s_sleep(1)
#else
#define SPIN_PAUSE()
#endif

// Compiler-level ordering fence (no ISA emitted). DS ops from one wave execute
// in order; this only stops the compiler from moving LDS accesses across the
// flag publish/poll points. (Pattern validated R3: absmax=0.)
#if __has_builtin(__builtin_amdgcn_wave_barrier)
#define WAVE_SYNC() do { __asm__ __volatile__("" ::: "memory"); __builtin_amdgcn_wave_barrier(); } while (0)
#else
#define WAVE_SYNC() __asm__ __volatile__("" ::: "memory")
#endif

__device__ __forceinline__ unsigned umin_(unsigned a, unsigned b) { return a < b ? a : b; }

// Pin 3-ary reductions to single instructions. Exact for non-NaN data; fp max
// is bitwise-selecting (order-independent), so any tree shape is bit-exact.
__device__ __forceinline__ float max3f(float a, float b, float c) {
    float d;
    asm("v_max3_f32 %0, %1, %2, %3" : "=v"(d) : "v"(a), "v"(b), "v"(c));
    return d;
}
__device__ __forceinline__ unsigned min3u(unsigned a, unsigned b, unsigned c) {
    unsigned d;
    asm("v_min3_u32 %0, %1, %2, %3" : "=v"(d) : "v"(a), "v"(b), "v"(c));
    return d;
}

#define CV(I_)  (cv2[(I_) / 2][(I_) & 1])
// d = cv_i - m is +0.0 (bits 0) iff cv_i == m, else negative (bits >= 0x80000000).
// bits(d)|i == i for max-tier, huge otherwise; umin -> lowest max-tier index
// == jnp.argmax first-occurrence tie-break, exactly. (Validated R8: absmax=0.)
#define UU(I_)  (__float_as_uint(d2[(I_) / 2][(I_) & 1]) | (unsigned)(I_))
#define EMIN3(I_) min3u(UU(I_), UU((I_) + 1), UU((I_) + 2))

__global__ __launch_bounds__(128, 2) void crf_viterbi(
    const float* __restrict__ pot,     // [B][T][C]
    const int*   __restrict__ seqlen,  // [B][1]
    const float* __restrict__ trans,   // [C][C]
    float*       __restrict__ out)     // [B][T][C] one-hot f32
{
    const int b    = blockIdx.x;
    const int tid  = threadIdx.x;       // 0..127
    const int lane = tid & 63;
    const int wid  = tid >> 6;          // 0 = producer (recurrence), 1 = consumer (argmax/bp)
    const int jj   = (lane < C_DIM) ? lane : (C_DIM - 1);  // clamped for safe loads

    __shared__ __align__(16) float sring[RING][64];      // s(t) rows, ring
    __shared__ __align__(16) float mring[RING][64];      // m_v(t) rows, ring
    __shared__ unsigned char bp[T_DIM * BPS];            // rows 1..L-1 used
    __shared__ __align__(4) unsigned char tags[T_DIM];
    __shared__ __align__(16) float fsc[64];              // final scores
    __shared__ volatile int prog0;                       // last t published by producer
    __shared__ volatile int prog1;                       // last t consumed by consumer

    const float* potb = pot + (size_t)b * (T_DIM * C_DIM);
    const int L   = seqlen[b];          // in [1, 511]
    const int thi = L - 1;

    // transitions column j as 24 packed pairs (both waves; clamped col for lanes >= 48)
    f32x2 tc2[24];
#pragma unroll
    for (int k = 0; k < 24; ++k) {
        tc2[k][0] = trans[(2 * k)     * C_DIM + jj];
        tc2[k][1] = trans[(2 * k + 1) * C_DIM + jj];
    }

    // init: producer stages s(0) = potentials[:,0] into ring row 0
    float ns = 0.0f;
    if (wid == 0) {
        ns = potb[jj];
        sring[0][lane] = ns;
    }
    if (tid == 0) { prog0 = 0; prog1 = 0; }
    __syncthreads();    // ring row 0 + flags visible to both waves

    if (wid == 0) {
        // ---------------- producer: serial max-plus recurrence ----------------
        const float* pp = potb + jj;
        float pb[CH];
#pragma unroll
        for (int k = 0; k < CH; ++k) {
            int tt = 1 + k; if (tt > T_DIM - 1) tt = T_DIM - 1;
            pb[k] = pp[tt * C_DIM];
        }
        for (int t0 = 1; t0 < L; t0 += CH) {
            float nb[CH];
#pragma unroll
            for (int k = 0; k < CH; ++k) {
                int tt = t0 + CH + k; if (tt > T_DIM - 1) tt = T_DIM - 1;
                nb[k] = pp[tt * C_DIM];
            }
            // ring space: chunk writes rows t0..t0+CH-1, overwriting rows t-RING.
            // s-row r is last used by consumer step r+1 -> need prog1 >= t-RING+1,
            // worst t = t0+CH-1  =>  prog1 >= t0 - (RING-CH).
            while (prog1 < t0 - (RING - CH)) { SPIN_PAUSE(); }
            WAVE_SYNC();
#pragma unroll
            for (int k = 0; k < CH; ++k) {
                const int t = t0 + k;
                if (t >= L) break;       // wave-uniform branch
                const f32x4* sp = (const f32x4*)sring[(t - 1) & RMASK];
                f32x2 cv2[24];
#pragma unroll
                for (int m = 0; m < 12; ++m) {
                    f32x4 sv = sp[m];
                    cv2[2 * m]     = sv.xy + tc2[2 * m];
                    cv2[2 * m + 1] = sv.zw + tc2[2 * m + 1];
                }
                float A0  = max3f(CV(0),  CV(1),  CV(2));
                float A1  = max3f(CV(3),  CV(4),  CV(5));
                float A2  = max3f(CV(6),  CV(7),  CV(8));
                float A3  = max3f(CV(9),  CV(10), CV(11));
                float A4  = max3f(CV(12), CV(13), CV(14));
                float A5  = max3f(CV(15), CV(16), CV(17));
                float A6  = max3f(CV(18), CV(19), CV(20));
                float A7  = max3f(CV(21), CV(22), CV(23));
                float A8  = max3f(CV(24), CV(25), CV(26));
                float A9  = max3f(CV(27), CV(28), CV(29));
                float A10 = max3f(CV(30), CV(31), CV(32));
                float A11 = max3f(CV(33), CV(34), CV(35));
                float A12 = max3f(CV(36), CV(37), CV(38));
                float A13 = max3f(CV(39), CV(40), CV(41));
                float A14 = max3f(CV(42), CV(43), CV(44));
                float A15 = max3f(CV(45), CV(46), CV(47));
                float B0 = max3f(A0,  A1,  A2);
                float B1 = max3f(A3,  A4,  A5);
                float B2 = max3f(A6,  A7,  A8);
                float B3 = max3f(A9,  A10, A11);
                float B4 = max3f(A12, A13, A14);
                float Cx0 = max3f(B0, B1, B2);
                float Cx1 = max3f(B3, B4, A15);
                const float m_v = fmaxf(Cx0, Cx1);
                ns = m_v + pb[k];
                mring[t & RMASK][lane] = m_v;
                sring[t & RMASK][lane] = ns;
            }
            WAVE_SYNC();                 // keep data writes above the flag publish
            {
                int td = t0 + CH - 1; if (td > thi) td = thi;
                prog0 = td;              // publish chunk
            }
#pragma unroll
            for (int k = 0; k < CH; ++k) pb[k] = nb[k];
        }
        fsc[lane] = ns;                  // final score vector
    } else {
        // ---------------- consumer: argmax encode + bp (throughput, no serial dep) ----
        for (int u0 = 1; u0 < L; u0 += CH) {
            int tgt = u0 + CH - 1; if (tgt > thi) tgt = thi;
            while (prog0 < tgt) { SPIN_PAUSE(); }
            WAVE_SYNC();                 // no hoisting of ring reads above poll
#pragma unroll
            for (int k = 0; k < CH; ++k) {
                const int u = u0 + k;
                if (u >= L) break;       // wave-uniform
                const f32x4* sp = (const f32x4*)sring[(u - 1) & RMASK];
                f32x2 cv2[24];
#pragma unroll
                for (int m = 0; m < 12; ++m) {
                    f32x4 sv = sp[m];
                    cv2[2 * m]     = sv.xy + tc2[2 * m];
                    cv2[2 * m + 1] = sv.zw + tc2[2 * m + 1];
                }
                const float m_v = mring[u & RMASK][lane];
                f32x2 d2[24];
                const f32x2 mv2 = {m_v, m_v};
#pragma unroll
                for (int q = 0; q < 24; ++q) d2[q] = cv2[q] - mv2;   // pk sub
                unsigned U0  = EMIN3(0);   unsigned U1  = EMIN3(3);
                unsigned U2  = EMIN3(6);   unsigned U3  = EMIN3(9);
                unsigned U4  = EMIN3(12);  unsigned U5  = EMIN3(15);
                unsigned U6  = EMIN3(18);  unsigned U7  = EMIN3(21);
                unsigned U8  = EMIN3(24);  unsigned U9  = EMIN3(27);
                unsigned U10 = EMIN3(30);  unsigned U11 = EMIN3(33);
                unsigned U12 = EMIN3(36);  unsigned U13 = EMIN3(39);
                unsigned U14 = EMIN3(42);  unsigned U15 = EMIN3(45);
                unsigned V0 = min3u(U0,  U1,  U2);
                unsigned V1 = min3u(U3,  U4,  U5);
                unsigned V2 = min3u(U6,  U7,  U8);
                unsigned V3 = min3u(U9,  U10, U11);
                unsigned V4 = min3u(U12, U13, U14);
                unsigned W0 = min3u(V0, V1, V2);
                unsigned W1 = min3u(V3, V4, U15);
                const unsigned wi_ = umin_(W0, W1);
                bp[u * BPS + lane] = (unsigned char)wi_;   // all 64 lanes; pad ok
            }
            WAVE_SYNC();                 // bp/ring reads stay above flag publish
            prog1 = tgt;
        }
    }
    __syncthreads();   // phase boundary: forward done, bp complete

    // last_tag = argmax over final scores (uniform LDS reads; both waves compute)
    const float* fs = fsc;
    float bv = fs[0];
    int   bi = 0;
#pragma unroll
    for (int i = 1; i < C_DIM; ++i) {
        float v = fs[i];
        if (v > bv) { bv = v; bi = i; }
    }
    const int last_tag = __builtin_amdgcn_readfirstlane(bi);

    // prefill tags[t] = last_tag for t in [L, T)   (all 128 threads)
    for (int t = L + tid; t < T_DIM; t += 128) tags[t] = (unsigned char)last_tag;

    // serial backtrace on wave 0 only:
    // for t = thi..1: tags[t] = y; y = bp[t][y];  then tags[0] = y
    if (wid == 0) {
        int y = last_tag;  // wave-uniform
        for (int c0 = (thi >> 6) << 6; c0 >= 0; c0 -= 64) {
            int row[64];   // row[k] holds bp[c0+k][jj] in lane jj
#pragma unroll
            for (int k = 0; k < 64; ++k) row[k] = bp[(c0 + k) * BPS + jj];

            int vacc = 0;
#pragma unroll
            for (int k = 63; k >= 0; --k) {
                const int t = c0 + k;
                vacc = (lane == k) ? y : vacc;                       // tags[t] = y (lane k)
                const int ynew = READLANE_I(row[k], y);
                if ((unsigned)(t - 1) < (unsigned)thi) y = ynew;     // update only t in [1, thi]
            }
            const int tk = c0 + lane;
            if (tk <= thi) tags[tk] = (unsigned char)(vacc & 0xff);
        }
    }
    __syncthreads();   // phase boundary

    // emit one-hot: 8 rows (t) per iteration, 96 lanes x float4 = 1536B coalesced
    if (tid < 96) {
        const int r = tid / 12;          // row-in-group 0..7
        const int q = tid - r * 12;      // float4 slot 0..11
        const int cbase = q * 4;
        float* ob = out + (size_t)b * (T_DIM * C_DIM);
        for (int t0 = 0; t0 < T_DIM; t0 += 8) {
            const int mytag = (int)tags[t0 + r];
            float4 v;
            v.x = (cbase + 0 == mytag) ? 1.0f : 0.0f;
            v.y = (cbase + 1 == mytag) ? 1.0f : 0.0f;
            v.z = (cbase + 2 == mytag) ? 1.0f : 0.0f;
            v.w = (cbase + 3 == mytag) ? 1.0f : 0.0f;
            *(float4*)(ob + (size_t)(t0 + r) * C_DIM + cbase) = v;
        }
    }
}

extern "C" void kernel_launch(void* const* d_in, const int* in_sizes, int n_in,
                              void* d_out, int out_size, void* d_ws, size_t ws_size,
                              hipStream_t stream) {
    const float* pot    = (const float*)d_in[0];
    const int*   sl     = (const int*)d_in[1];
    const float* trans  = (const float*)d_in[2];
    float*       out    = (float*)d_out;
    const int B = in_sizes[1];  // sequence_lengths has B elements
    crf_viterbi<<<B, 128, 0, stream>>>(pot, sl, trans, out);
}

// Round 5
// 422.313 us; speedup vs baseline: 1.1870x; 1.1870x over previous
//
#include <hip/hip_runtime.h>

#define T_DIM 512
#define C_DIM 48
#define BPS   48          // bp row stride (store masked to lanes < 48)
#define CH    4           // chunk: prefetch distance, ring-sync granularity
#define RING  16          // score/max ring rows (power of 2); slack = RING-CH = 12
#define RMASK (RING - 1)

typedef float f32x2 __attribute__((ext_vector_type(2)));
typedef float f32x4 __attribute__((ext_vector_type(4)));

#if __has_builtin(__builtin_amdgcn_readlane)
#define READLANE_I(v, l) __builtin_amdgcn_readlane((v), (l))
#else
#define READLANE_I(v, l) __shfl((v), (l), 64)
#endif

#if __has_builtin(__builtin_amdgcn_s_sleep)
#define SPIN_PAUSE() __builtin_amdgcn_s_sleep(1)
#else
#define SPIN_PAUSE()
#endif

// Compiler-level ordering fence (no ISA emitted). DS ops from one wave execute
// in order; this only stops the compiler from moving LDS accesses across the
// flag publish/poll points. (Pattern validated R3/R4: absmax=0.)
#if __has_builtin(__builtin_amdgcn_wave_barrier)
#define WAVE_SYNC() do { __asm__ __volatile__("" ::: "memory"); __builtin_amdgcn_wave_barrier(); } while (0)
#else
#define WAVE_SYNC() __asm__ __volatile__("" ::: "memory")
#endif

__device__ __forceinline__ unsigned umin_(unsigned a, unsigned b) { return a < b ? a : b; }

// Pin 3-ary reductions to single instructions. Exact for non-NaN data; fp max
// is bitwise-selecting (order-independent), so any tree shape is bit-exact.
__device__ __forceinline__ float max3f(float a, float b, float c) {
    float d;
    asm("v_max3_f32 %0, %1, %2, %3" : "=v"(d) : "v"(a), "v"(b), "v"(c));
    return d;
}
__device__ __forceinline__ unsigned min3u(unsigned a, unsigned b, unsigned c) {
    unsigned d;
    asm("v_min3_u32 %0, %1, %2, %3" : "=v"(d) : "v"(a), "v"(b), "v"(c));
    return d;
}

#define CV(I_)  (cv2[(I_) / 2][(I_) & 1])
// d = cv_i - m is +0.0 (bits 0) iff cv_i == m, else negative (bits >= 0x80000000).
// bits(d)|i == i for max-tier, huge otherwise; umin -> lowest max-tier index
// == jnp.argmax first-occurrence tie-break, exactly. (Validated R8: absmax=0.)
#define UU(I_)  (__float_as_uint(d2[(I_) / 2][(I_) & 1]) | (unsigned)(I_))
#define EMIN3(I_) min3u(UU(I_), UU((I_) + 1), UU((I_) + 2))

__global__ __launch_bounds__(128, 2) void crf_viterbi(
    const float* __restrict__ pot,     // [B][T][C]
    const int*   __restrict__ seqlen,  // [B][1]
    const float* __restrict__ trans,   // [C][C]
    float*       __restrict__ out)     // [B][T][C] one-hot f32
{
    const int b    = blockIdx.x;
    const int tid  = threadIdx.x;       // 0..127
    const int lane = tid & 63;
    const int wid  = tid >> 6;          // 0 = producer (recurrence), 1 = consumer (argmax/bp)
    const int jj   = (lane < C_DIM) ? lane : (C_DIM - 1);  // clamped for safe loads

    __shared__ __align__(16) float sring[RING][64];      // s(t) rows, ring (48 used)
    __shared__ __align__(16) float mring[RING][64];      // m_v(t) rows, ring
    __shared__ unsigned char bp[T_DIM * BPS];            // rows 1..L-1 used
    __shared__ __align__(4) unsigned char tags[T_DIM];
    __shared__ __align__(16) float fsc[64];              // final scores
    __shared__ volatile int prog0;                       // last t published by producer
    __shared__ volatile int prog1;                       // last t consumed by consumer

    const float* potb = pot + (size_t)b * (T_DIM * C_DIM);
    const int L   = seqlen[b];          // in [1, 511]
    const int thi = L - 1;

    // transitions column j as 24 packed pairs (both waves; clamped col for lanes >= 48)
    f32x2 tc2[24];
#pragma unroll
    for (int k = 0; k < 24; ++k) {
        tc2[k][0] = trans[(2 * k)     * C_DIM + jj];
        tc2[k][1] = trans[(2 * k + 1) * C_DIM + jj];
    }

    // init: producer stages s(0) = potentials[:,0] into ring row 0
    float ns = 0.0f;
    if (wid == 0) {
        ns = potb[jj];
        sring[0][lane] = ns;
    }
    if (tid == 0) { prog0 = 0; prog1 = 0; }
    __syncthreads();    // ring row 0 + flags visible to both waves

    if (wid == 0) {
        // ---------------- producer: serial max-plus recurrence (issue-light) --------
        const float* pp = potb + jj;
        float pb[CH];
#pragma unroll
        for (int k = 0; k < CH; ++k) {
            int tt = 1 + k; if (tt > T_DIM - 1) tt = T_DIM - 1;
            pb[k] = pp[tt * C_DIM];
        }
        for (int t0 = 1; t0 < L; t0 += CH) {
            float nb[CH];
#pragma unroll
            for (int k = 0; k < CH; ++k) {
                int tt = t0 + CH + k; if (tt > T_DIM - 1) tt = T_DIM - 1;
                nb[k] = pp[tt * C_DIM];
            }
            // ring space: chunk writes rows t0..t0+CH-1 (mod RING), destroying rows
            // t-RING. Row r is last needed by consumer step r+1, so require
            // prog1 >= (t0+CH-1) - RING + 1  ==  t0 - (RING - CH).   Slack: 3 chunks.
            while (prog1 < t0 - (RING - CH)) { SPIN_PAUSE(); }
            WAVE_SYNC();
#pragma unroll
            for (int k = 0; k < CH; ++k) {
                const int t = t0 + k;
                if (t >= L) break;       // wave-uniform branch
                const f32x4* sp = (const f32x4*)sring[(t - 1) & RMASK];
                f32x2 cv2[24];
#pragma unroll
                for (int m = 0; m < 12; ++m) {
                    f32x4 sv = sp[m];
                    cv2[2 * m]     = sv.xy + tc2[2 * m];
                    cv2[2 * m + 1] = sv.zw + tc2[2 * m + 1];
                }
                float A0  = max3f(CV(0),  CV(1),  CV(2));
                float A1  = max3f(CV(3),  CV(4),  CV(5));
                float A2  = max3f(CV(6),  CV(7),  CV(8));
                float A3  = max3f(CV(9),  CV(10), CV(11));
                float A4  = max3f(CV(12), CV(13), CV(14));
                float A5  = max3f(CV(15), CV(16), CV(17));
                float A6  = max3f(CV(18), CV(19), CV(20));
                float A7  = max3f(CV(21), CV(22), CV(23));
                float A8  = max3f(CV(24), CV(25), CV(26));
                float A9  = max3f(CV(27), CV(28), CV(29));
                float A10 = max3f(CV(30), CV(31), CV(32));
                float A11 = max3f(CV(33), CV(34), CV(35));
                float A12 = max3f(CV(36), CV(37), CV(38));
                float A13 = max3f(CV(39), CV(40), CV(41));
                float A14 = max3f(CV(42), CV(43), CV(44));
                float A15 = max3f(CV(45), CV(46), CV(47));
                float B0 = max3f(A0,  A1,  A2);
                float B1 = max3f(A3,  A4,  A5);
                float B2 = max3f(A6,  A7,  A8);
                float B3 = max3f(A9,  A10, A11);
                float B4 = max3f(A12, A13, A14);
                float Cx0 = max3f(B0, B1, B2);
                float Cx1 = max3f(B3, B4, A15);
                const float m_v = fmaxf(Cx0, Cx1);
                ns = m_v + pb[k];
                mring[t & RMASK][lane] = m_v;
                sring[t & RMASK][lane] = ns;
            }
            WAVE_SYNC();                 // keep data writes above the flag publish
            {
                int td = t0 + CH - 1; if (td > thi) td = thi;
                prog0 = td;              // publish chunk
            }
#pragma unroll
            for (int k = 0; k < CH; ++k) pb[k] = nb[k];
        }
        fsc[lane] = ns;                  // final score vector
    } else {
        // ---------------- consumer: argmax encode + bp (independent steps) ---------
        for (int u0 = 1; u0 < L; u0 += CH) {
            int tgt = u0 + CH - 1; if (tgt > thi) tgt = thi;
            while (prog0 < tgt) { SPIN_PAUSE(); }
            WAVE_SYNC();                 // no hoisting of ring reads above poll
#pragma unroll
            for (int k = 0; k < CH; ++k) {
                const int u = u0 + k;
                if (u >= L) break;       // wave-uniform
                const f32x4* sp = (const f32x4*)sring[(u - 1) & RMASK];
                f32x2 cv2[24];
#pragma unroll
                for (int m = 0; m < 12; ++m) {
                    f32x4 sv = sp[m];
                    cv2[2 * m]     = sv.xy + tc2[2 * m];
                    cv2[2 * m + 1] = sv.zw + tc2[2 * m + 1];
                }
                const float m_v = mring[u & RMASK][lane];
                f32x2 d2[24];
                const f32x2 mv2 = {m_v, m_v};
#pragma unroll
                for (int q = 0; q < 24; ++q) d2[q] = cv2[q] - mv2;   // pk sub
                unsigned U0  = EMIN3(0);   unsigned U1  = EMIN3(3);
                unsigned U2  = EMIN3(6);   unsigned U3  = EMIN3(9);
                unsigned U4  = EMIN3(12);  unsigned U5  = EMIN3(15);
                unsigned U6  = EMIN3(18);  unsigned U7  = EMIN3(21);
                unsigned U8  = EMIN3(24);  unsigned U9  = EMIN3(27);
                unsigned U10 = EMIN3(30);  unsigned U11 = EMIN3(33);
                unsigned U12 = EMIN3(36);  unsigned U13 = EMIN3(39);
                unsigned U14 = EMIN3(42);  unsigned U15 = EMIN3(45);
                unsigned V0 = min3u(U0,  U1,  U2);
                unsigned V1 = min3u(U3,  U4,  U5);
                unsigned V2 = min3u(U6,  U7,  U8);
                unsigned V3 = min3u(U9,  U10, U11);
                unsigned V4 = min3u(U12, U13, U14);
                unsigned W0 = min3u(V0, V1, V2);
                unsigned W1 = min3u(V3, V4, U15);
                const unsigned wi_ = umin_(W0, W1);
                if (lane < C_DIM) bp[u * BPS + lane] = (unsigned char)wi_;
            }
            WAVE_SYNC();                 // bp/ring reads stay above flag publish
            prog1 = tgt;
        }
    }
    __syncthreads();   // phase boundary: forward done, bp complete

    // last_tag = argmax over final scores (uniform LDS reads; both waves compute)
    const float* fs = fsc;
    float bv = fs[0];
    int   bi = 0;
#pragma unroll
    for (int i = 1; i < C_DIM; ++i) {
        float v = fs[i];
        if (v > bv) { bv = v; bi = i; }
    }
    const int last_tag = __builtin_amdgcn_readfirstlane(bi);

    // prefill tags[t] = last_tag for t in [L, T)   (all 128 threads)
    for (int t = L + tid; t < T_DIM; t += 128) tags[t] = (unsigned char)last_tag;

    // serial backtrace on wave 0 only:
    // for t = thi..1: tags[t] = y; y = bp[t][y];  then tags[0] = y
    if (wid == 0) {
        int y = last_tag;  // wave-uniform
        for (int c0 = (thi >> 6) << 6; c0 >= 0; c0 -= 64) {
            int row[64];   // row[k] holds bp[c0+k][jj] in lane jj
#pragma unroll
            for (int k = 0; k < 64; ++k) row[k] = bp[(c0 + k) * BPS + jj];

            int vacc = 0;
#pragma unroll
            for (int k = 63; k >= 0; --k) {
                const int t = c0 + k;
                vacc = (lane == k) ? y : vacc;                       // tags[t] = y (lane k)
                const int ynew = READLANE_I(row[k], y);
                if ((unsigned)(t - 1) < (unsigned)thi) y = ynew;     // update only t in [1, thi]
            }
            const int tk = c0 + lane;
            if (tk <= thi) tags[tk] = (unsigned char)(vacc & 0xff);
        }
    }
    __syncthreads();   // phase boundary

    // emit one-hot: 8 rows (t) per iteration, 96 lanes x float4 = 1536B coalesced
    if (tid < 96) {
        const int r = tid / 12;          // row-in-group 0..7
        const int q = tid - r * 12;      // float4 slot 0..11
        const int cbase = q * 4;
        float* ob = out + (size_t)b * (T_DIM * C_DIM);
        for (int t0 = 0; t0 < T_DIM; t0 += 8) {
            const int mytag = (int)tags[t0 + r];
            float4 v;
            v.x = (cbase + 0 == mytag) ? 1.0f : 0.0f;
            v.y = (cbase + 1 == mytag) ? 1.0f : 0.0f;
            v.z = (cbase + 2 == mytag) ? 1.0f : 0.0f;
            v.w = (cbase + 3 == mytag) ? 1.0f : 0.0f;
            *(float4*)(ob + (size_t)(t0 + r) * C_DIM + cbase) = v;
        }
    }
}

extern "C" void kernel_launch(void* const* d_in, const int* in_sizes, int n_in,
                              void* d_out, int out_size, void* d_ws, size_t ws_size,
                              hipStream_t stream) {
    const float* pot    = (const float*)d_in[0];
    const int*   sl     = (const int*)d_in[1];
    const float* trans  = (const float*)d_in[2];
    float*       out    = (float*)d_out;
    const int B = in_sizes[1];  // sequence_lengths has B elements
    crf_viterbi<<<B, 128, 0, stream>>>(pot, sl, trans, out);
}

// Round 6
// 289.368 us; speedup vs baseline: 1.7323x; 1.4594x over previous
//
#include <hip/hip_runtime.h>

#define T_DIM 512
#define C_DIM 48
#define BPS   48          // bp row stride; 16-lane spill into next row is benign (see store)
#define CH    4           // global-prefetch chunk

#if __has_builtin(__builtin_amdgcn_readlane)
#define READLANE_I(v, l) __builtin_amdgcn_readlane((v), (l))
#else
#define READLANE_I(v, l) __shfl((v), (l), 64)
#endif

// Compiler-level ordering fence for single-wave LDS communication.
#if __has_builtin(__builtin_amdgcn_wave_barrier)
#define WAVE_SYNC() do { __asm__ __volatile__("" ::: "memory"); __builtin_amdgcn_wave_barrier(); } while (0)
#else
#define WAVE_SYNC() __asm__ __volatile__("" ::: "memory")
#endif

// One DPP max-reduce step: lanes with invalid source keep their own value
// (old = v, bound_ctrl = false), so max semantics are preserved.
#define DPP_MAX_STEP(V_, CTRL_) do {                                          \
    int o_ = __builtin_amdgcn_update_dpp(__float_as_int(V_),                  \
                                         __float_as_int(V_),                  \
                                         (CTRL_), 0xF, 0xF, false);           \
    V_ = fmaxf(V_, __int_as_float(o_));                                       \
} while (0)

// Full-wave f32 max (VALU-only, no LDS pipe): row_shr 1/2/4/8 then
// row_bcast:15, row_bcast:31; lane 63 holds the wave max -> broadcast.
// Lanes 48-63 hold duplicates of lane 47 in all uses here (harmless for max).
__device__ __forceinline__ float wave_max_f(float v) {
    DPP_MAX_STEP(v, 0x111);   // row_shr:1
    DPP_MAX_STEP(v, 0x112);   // row_shr:2
    DPP_MAX_STEP(v, 0x114);   // row_shr:4
    DPP_MAX_STEP(v, 0x118);   // row_shr:8
    DPP_MAX_STEP(v, 0x142);   // row_bcast:15
    DPP_MAX_STEP(v, 0x143);   // row_bcast:31
    return __int_as_float(READLANE_I(__float_as_int(v), 63));
}

__global__ __launch_bounds__(64) void crf_viterbi(
    const float* __restrict__ pot,     // [B][T][C]
    const int*   __restrict__ seqlen,  // [B][1]
    const float* __restrict__ trans,   // [C][C]
    float*       __restrict__ out)     // [B][T][C] one-hot f32
{
    const int b   = blockIdx.x;
    const int tid = threadIdx.x;
    const int jj  = (tid < C_DIM) ? tid : (C_DIM - 1);  // clamped for safe loads

    __shared__ __align__(16) float trl[C_DIM * C_DIM];   // transitions, row-major
    __shared__ unsigned char bp[T_DIM * BPS];            // rows 1..L-1 used
    __shared__ __align__(4) unsigned char tags[T_DIM];
    __shared__ __align__(16) float fsc[64];              // final scores

    const float* potb = pot + (size_t)b * (T_DIM * C_DIM);
    const int L   = seqlen[b];          // in [1, 511]
    const int thi = L - 1;

    // ---- stage transitions into LDS (coalesced) + compute tmax = max|Tr| ----
    float tm = 0.0f;
    for (int i = tid; i < C_DIM * C_DIM; i += 64) {      // 36 iters exactly
        float v = trans[i];
        trl[i] = v;
        tm = fmaxf(tm, fabsf(v));
    }
    const float tmax = wave_max_f(tm);                   // uniform
    const float nC5 = -(5.0f * tmax + 1e-3f);            // steady-state margin
    const float nC2 = -(2.0f * tmax + 1e-3f);            // prologue margin
    WAVE_SYNC();                                         // trl visible (same wave)

    // ---- init: lane j holds s(0)[j]; thr(1) from exact s_max(0) ----
    float ns = potb[jj];
    float vthr = wave_max_f(ns) + nC2;

    const float* pp = potb + jj;

    // ---- prefetch pot rows + per-row pmax (input-only, off the chain) ----
    float pb[CH];
    float pmr[CH];
#pragma unroll
    for (int k = 0; k < CH; ++k) {
        int tt = 1 + k; if (tt > T_DIM - 1) tt = T_DIM - 1;
        pb[k] = pp[tt * C_DIM];
    }
#pragma unroll
    for (int k = 0; k < CH; ++k) pmr[k] = wave_max_f(pb[k]);

    for (int t0 = 1; t0 < L; t0 += CH) {
        float nb[CH];
#pragma unroll
        for (int k = 0; k < CH; ++k) {
            int tt = t0 + CH + k; if (tt > T_DIM - 1) tt = T_DIM - 1;
            nb[k] = pp[tt * C_DIM];
        }
#pragma unroll
        for (int k = 0; k < CH; ++k) {
            const int t = t0 + k;
            if (t >= L) break;           // wave-uniform branch
            // ---- candidate-pruned Viterbi step ----
            // Winner i* for any j satisfies s_i* >= s_max - 2*tmax; vthr is a
            // proven lower bound of s_max - 2*tmax - slack  => superset mask.
            unsigned long long mm =
                __ballot(ns >= vthr) & 0x0000FFFFFFFFFFFFull;
            if (!mm) mm = 0x0000FFFFFFFFFFFFull;         // defensive: full argmax
            int c = (int)__builtin_ctzll(mm); mm &= mm - 1;
            float s_c = __int_as_float(READLANE_I(__float_as_int(ns), c));
            float m  = s_c + trl[c * C_DIM + jj];        // exact same add as ref
            int   wi = c;
            while (mm) {                                 // usually 0-1 iterations
                int c2 = (int)__builtin_ctzll(mm); mm &= mm - 1;
                float s2 = __int_as_float(READLANE_I(__float_as_int(ns), c2));
                float cv = s2 + trl[c2 * C_DIM + jj];
                bool g = cv > m;                         // strict: first-occurrence
                m  = g ? cv : m;
                wi = g ? c2 : wi;
            }
            // bp store: all 64 lanes; lanes 48-63 spill into row t+1 cols 0-15,
            // which is overwritten next step (or is row thi+1 <= 511: never read).
            bp[t * BPS + tid] = (unsigned char)wi;
            ns   = m + pb[k];                            // exact same add as ref
            vthr = (m + pmr[k]) + nC5;                   // thr(t+1), per-lane valid
        }
        // next-chunk pmax reduces (nb latency already covered by the 4 steps)
        float pmn[CH];
#pragma unroll
        for (int k = 0; k < CH; ++k) pmn[k] = wave_max_f(nb[k]);
#pragma unroll
        for (int k = 0; k < CH; ++k) { pb[k] = nb[k]; pmr[k] = pmn[k]; }
    }

    // publish final scores
    fsc[tid] = ns;
    WAVE_SYNC();
    __syncthreads();   // phase boundary (single wave; cheap)

    // last_tag = argmax over final scores (uniform LDS reads, broadcast)
    const float* fs = fsc;
    float bv = fs[0];
    int   bi = 0;
#pragma unroll
    for (int i = 1; i < C_DIM; ++i) {
        float v = fs[i];
        if (v > bv) { bv = v; bi = i; }
    }
    const int last_tag = __builtin_amdgcn_readfirstlane(bi);

    // prefill tags[t] = last_tag for t in [L, T)
    for (int t = L + tid; t < T_DIM; t += 64) tags[t] = (unsigned char)last_tag;

    // serial backtrace: for t = thi..1: tags[t] = y; y = bp[t][y];  then tags[0] = y
    int y = last_tag;  // wave-uniform
    for (int c0 = (thi >> 6) << 6; c0 >= 0; c0 -= 64) {
        int row[64];   // row[k] holds bp[c0+k][jj] in lane jj
#pragma unroll
        for (int k = 0; k < 64; ++k) row[k] = bp[(c0 + k) * BPS + jj];

        int vacc = 0;
#pragma unroll
        for (int k = 63; k >= 0; --k) {
            const int t = c0 + k;
            vacc = (tid == k) ? y : vacc;                        // tags[t] = y (lane k)
            const int ynew = READLANE_I(row[k], y);
            if ((unsigned)(t - 1) < (unsigned)thi) y = ynew;     // update only t in [1, thi]
        }
        const int tk = c0 + tid;
        if (tk <= thi) tags[tk] = (unsigned char)(vacc & 0xff);
    }
    __syncthreads();   // phase boundary

    // emit one-hot: 4 rows (t) per iteration, 48 lanes x float4 = 768B coalesced
    if (tid < C_DIM) {
        const int r = tid / 12;          // row-in-group 0..3
        const int q = tid - r * 12;      // float4 slot 0..11
        const int cbase = q * 4;
        float* ob = out + (size_t)b * (T_DIM * C_DIM);
        for (int t0 = 0; t0 < T_DIM; t0 += 4) {
            const unsigned int tg4 = *(const unsigned int*)&tags[t0];
            const int mytag = (int)((tg4 >> (r * 8)) & 0xffu);
            float4 v;
            v.x = (cbase + 0 == mytag) ? 1.0f : 0.0f;
            v.y = (cbase + 1 == mytag) ? 1.0f : 0.0f;
            v.z = (cbase + 2 == mytag) ? 1.0f : 0.0f;
            v.w = (cbase + 3 == mytag) ? 1.0f : 0.0f;
            *(float4*)(ob + (size_t)(t0 + r) * C_DIM + cbase) = v;
        }
    }
}

extern "C" void kernel_launch(void* const* d_in, const int* in_sizes, int n_in,
                              void* d_out, int out_size, void* d_ws, size_t ws_size,
                              hipStream_t stream) {
    const float* pot    = (const float*)d_in[0];
    const int*   sl     = (const int*)d_in[1];
    const float* trans  = (const float*)d_in[2];
    float*       out    = (float*)d_out;
    const int B = in_sizes[1];  // sequence_lengths has B elements
    crf_viterbi<<<B, 64, 0, stream>>>(pot, sl, trans, out);
}